// Round 8
// baseline (664.960 us; speedup 1.0000x reference)
//
#include <hip/hip_runtime.h>

#define PI_D 3.14159265358979323846

// Layouts
//  x[l2,part]: (8192, 15, l2+1, 5, 16) fp32  n-stride = 1200*(l2+1)
//  w[l1,part]: (l1+1, 15, 5, 16, 16)  fp32
//  b[l,part]:  (1, l+1, 5, 16)        fp32
//  out[l,part]:(8192, l+1, 5, 16) concat; base = 655360*(l+1)*(l+part)
// K (4800): l2{partp{kx{t{i16}}}}; kb offsets 0,30,90,180. col (320): l{part{lr{j16}}}
// ws: G[16384] f32 @0; W'[p][col][K] bf16 @64KB (15.36MB); Xp[p][n][K] bf16 @16MB (393MB)
// Xp is slot-swizzled: 16-B slot s (=K/8) stored at s ^ (n&7) within each 64-K octet.

typedef __attribute__((ext_vector_type(8))) short short8;
typedef __attribute__((ext_vector_type(4))) float f32x4;

struct Ptrs8 { const float* p[8]; };

__device__ __forceinline__ ushort f2bf(float x){
  uint u = __float_as_uint(x);
  return (ushort)((u + 0x7fffu + ((u>>16)&1u)) >> 16);
}

__device__ __forceinline__ void gload16(const void* g, ushort* l){
  __builtin_amdgcn_global_load_lds((const __attribute__((address_space(1))) void*)g,
                                   (__attribute__((address_space(3))) void*)l, 16, 0, 0);
}

__device__ __forceinline__ double dfact(int n){ double r=1.0; for(int i=2;i<=n;++i) r*=(double)i; return r; }

__device__ double cg_coef(int j1,int m1,int j2,int m2,int j3,int m3){
  if(m1+m2!=m3) return 0.0;
  if(j3<abs(j1-j2)||j3>j1+j2) return 0.0;
  if(abs(m1)>j1||abs(m2)>j2||abs(m3)>j3) return 0.0;
  double pre = sqrt((2.0*j3+1.0)*dfact(j3+j1-j2)*dfact(j3-j1+j2)*dfact(j1+j2-j3)/dfact(j1+j2+j3+1));
  pre *= sqrt(dfact(j3+m3)*dfact(j3-m3)*dfact(j1-m1)*dfact(j1+m1)*dfact(j2-m2)*dfact(j2+m2));
  int kmin = max(0,max(j2-j3-m1,j1-j3+m2));
  int kmax = min(j1+j2-j3,min(j1-m1,j2+m2));
  double s=0.0;
  for(int k=kmin;k<=kmax;++k){
    double d = dfact(k)*dfact(j1+j2-j3-k)*dfact(j1-m1-k)*dfact(j2+m2-k)*dfact(j3-j2+m1+k)*dfact(j3-j1-m2+k);
    s += ((k&1)?-1.0:1.0)/d;
  }
  return pre*s;
}

__device__ __forceinline__ int gidx(int l,int l2,int combo,int lr,int kx,int l1,int m){
  return ((((((l*4+l2)*4+combo)*4+lr)*4+kx)*4+l1)*4+m);
}

__global__ void g_kernel(float* __restrict__ G){
  int tid = threadIdx.x;
  for(int e=tid;e<16384;e+=blockDim.x) G[e]=0.0f;
  __syncthreads();
  int trip = tid >> 4;
  int sub  = tid & 15;
  int lr = sub >> 2, m = sub & 3;
  int idx=0;
  for(int l=0;l<4;l++)for(int l1=0;l1<4;l1++){
    int lo=abs(l-l1), hi=min(3,l+l1);
    for(int l2=lo;l2<=hi;l2++){
      if(idx==trip && lr<=l && m<=l1){
        double c = 8.0*PI_D*PI_D/(2.0*l1+1.0)
                 * sqrt((2.0*l+1.0)*(2.0*l1+1.0)/(4.0*PI_D*(2.0*l2+1.0)))
                 * cg_coef(l,0,l1,0,l2,0);
        if(lr+m<=l2){
          float f = (float)(c * cg_coef(l,lr,l1,m,l2,lr+m) * ((m&1)?-1.0:1.0));
          G[gidx(l,l2,0,lr,lr+m,l1,m)] += f;
          G[gidx(l,l2,1,lr,lr+m,l1,m)] -= f;
          G[gidx(l,l2,2,lr,lr+m,l1,m)] += f;
          G[gidx(l,l2,3,lr,lr+m,l1,m)] += f;
        }
        if(m>0 && abs(lr-m)<=l2){
          if(lr-m>=0){
            float f = (float)(c * cg_coef(l,lr,l1,-m,l2,lr-m) * ((l1&1)?-1.0:1.0));
            G[gidx(l,l2,0,lr,lr-m,l1,m)] += f;
            G[gidx(l,l2,1,lr,lr-m,l1,m)] += f;
            G[gidx(l,l2,2,lr,lr-m,l1,m)] -= f;
            G[gidx(l,l2,3,lr,lr-m,l1,m)] += f;
          } else {
            float f = (float)(c * (((m-lr)&1)?-1.0:1.0) * (((l1+l2)&1)?-1.0:1.0)
                              * cg_coef(l,lr,l1,-m,l2,lr-m));
            G[gidx(l,l2,0,lr,m-lr,l1,m)] += f;
            G[gidx(l,l2,1,lr,m-lr,l1,m)] -= f;
            G[gidx(l,l2,2,lr,m-lr,l1,m)] -= f;
            G[gidx(l,l2,3,lr,m-lr,l1,m)] -= f;
          }
        }
      }
      idx++;
    }
  }
}

__device__ __forceinline__ void decode_kb(int kb,int& l2,int& partp,int& kx,int& t){
  int kbo;
  if(kb<30){l2=0;kbo=0;} else if(kb<90){l2=1;kbo=30;} else if(kb<180){l2=2;kbo=90;} else {l2=3;kbo=180;}
  int rem = kb-kbo;
  int per = (l2+1)*15;
  partp = rem/per;
  int q = rem%per;
  kx = q/15; t = q%15;
}

__device__ __forceinline__ void decode_col(int col,int& l,int& part,int& lr,int& j){
  int co;
  if(col<32){l=0;co=0;} else if(col<96){l=1;co=32;} else if(col<192){l=2;co=96;} else {l=3;co=192;}
  int cr = col-co; int per=(l+1)*16;
  part = cr/per; int q = cr%per; lr = q>>4; j = q&15;
}

// W'[p][col][K] bf16
__global__ void w_kernel(const float* __restrict__ G, Ptrs8 wp, ushort* __restrict__ W){
  long e = (long)blockIdx.x*256 + threadIdx.x;
  if(e >= 5L*320*4800) return;
  int K = (int)(e%4800); long r = e/4800; int col = (int)(r%320); int p = (int)(r/320);
  int i = K & 15; int kb = K >> 4;
  int l2,partp,kx,t; decode_kb(kb,l2,partp,kx,t);
  int l,part,lr,j; decode_col(col,l,part,lr,j);
  int combo = (part==0) ? (partp==0?0:1) : (partp==0?2:3);
  int wpart = (combo==0||combo==3)?0:1;
  int mstart = wpart?1:0;
  int woff = t*1280 + p*256 + i*16 + j;
  float acc=0.f;
  for(int l1=0;l1<4;l1++){
    const float* wptr = wp.p[l1*2+wpart];
    int gb = ((((l*4+l2)*4+combo)*4+lr)*4+kx)*16 + l1*4;
    for(int m=mstart;m<=l1;m++){
      float g = G[gb+m];
      if(g!=0.f) acc += g * wptr[m*19200 + woff];
    }
  }
  W[e] = f2bf(acc);
}

// ---------------- pack: x (fp32, n-major) -> Xp[p][n][K] bf16, slot-swizzled --
// One block per n-row. Reads each array's row fully contiguously (full BW);
// writes 5 contiguous 9600-B runs. LDS stride padded (4816) to spread banks.
__global__ __launch_bounds__(256) void pack_kernel(Ptrs8 xp, ushort* __restrict__ Xp){
  __shared__ ushort L[5*4816];
  const int tid = threadIdx.x;
  const int n = blockIdx.x;
  const int nsw = (n & 7) << 3;   // swizzle on slot -> ushort-idx bits 3..5
  #pragma unroll
  for(int a=0;a<8;a++){
    const int l2 = a>>1, partp = a&1;
    const int kbo = (l2==0)?0:(l2==1)?30:(l2==2)?90:180;
    const int kbase = kbo + partp*15*(l2+1);
    const float* row = xp.p[a] + (long)n*1200*(l2+1);
    const int nf4 = 300*(l2+1);
    for(int u=tid; u<nf4; u+=256){
      float4 v = ((const float4*)row)[u];
      int f = u*4;
      int i = f & 15;
      int r = f >> 4;             // = (t*(l2+1)+kx)*5 + p
      int p = r % 5;
      int tk = r / 5;
      int kx = tk % (l2+1);
      int t  = tk / (l2+1);
      int K = (kbase + kx*15 + t)*16 + i;
      int idx = p*4816 + ((((K>>3)*8) ^ nsw)) + (K&7);
      uint2 d;
      d.x = (uint)f2bf(v.x) | ((uint)f2bf(v.y)<<16);
      d.y = (uint)f2bf(v.z) | ((uint)f2bf(v.w)<<16);
      *(uint2*)(&L[idx]) = d;
    }
  }
  __syncthreads();
  // drain: 5 x 600 uint4 per row
  for(int u=tid; u<3000; u+=256){
    int p = u/600, b = u - p*600;
    const uint4 s = *(const uint4*)(&L[p*4816 + b*8]);
    *(uint4*)((char*)Xp + ((long)p*8192 + n)*9600 + b*16) = s;
  }
}

// ---------------- GEMM (packed): out[8192x320] = Xp[p] * W'[p], per p --------
// 64-row x 320-col tile, 4 waves (80 cols each). A via global_load_lds into
// 3 LDS chunk-buffers of 192 K (24576 B); counted vmcnt (never 0); one raw
// barrier per chunk (3 kt). B reg-rolling 3-deep from L2.

__device__ __forceinline__ void b_load(const ushort* Wp,int w,int lane,int kt,short8* b){
  const ushort* q = Wp + (long)(w*80 + (lane&15))*4800 + kt*64 + ((lane>>4)*8);
  #pragma unroll
  for(int ks=0;ks<2;++ks)
    #pragma unroll
    for(int ni=0;ni<5;++ni)
      b[ks*5+ni] = *(const short8*)(q + (long)ni*16*4800 + ks*32);
}

__device__ __forceinline__ void do_mfma192(const ushort* A,int ktl,int lane,const short8* b,f32x4 acc[4][5]){
  #pragma unroll
  for(int ks=0;ks<2;++ks){
    short8 af[4];
    #pragma unroll
    for(int mi=0;mi<4;++mi){
      int nn = mi*16 + (lane&15);
      int idx = nn*192 + ((ktl*64 + ks*32 + ((lane>>4)<<3)) ^ ((nn&7)<<3));
      af[mi] = *(const short8*)(A + idx);
    }
    #pragma unroll
    for(int mi=0;mi<4;++mi)
      #pragma unroll
      for(int ni=0;ni<5;++ni)
        acc[mi][ni] = __builtin_amdgcn_mfma_f32_16x16x32_bf16(af[mi], b[ks*5+ni], acc[mi][ni], 0,0,0);
  }
}

__device__ __forceinline__ void stageA(const char* Xb,const int* srcb,int cc,ushort* buf,int w){
  #pragma unroll
  for(int c6=0;c6<6;++c6)
    gload16(Xb + srcb[c6] + cc*384, buf + ((c6*4096 + w*1024)>>1));
}

__global__ __launch_bounds__(256,2) void gemm_xp(const ushort* __restrict__ Xp,
                                                 const ushort* __restrict__ Wb,
                                                 Ptrs8 bp, float* __restrict__ out){
  __shared__ ushort As[3][12288];   // 3 x 24576 B
  const int tid = threadIdx.x;
  const int lane = tid & 63;
  const int w = tid >> 6;
  int orig = blockIdx.x;
  int wg = (orig & 7)*80 + (orig >> 3);   // XCD-chunked: ~one p-slice per XCD
  const int p = wg / 128;
  const int nb = wg % 128;
  const int n0 = nb*64;
  const ushort* Wp = Wb + (long)p*320*4800;
  const char* Xb = (const char*)Xp + (long)p*8192*9600;

  int srcb[6];
  #pragma unroll
  for(int c6=0;c6<6;++c6){
    int o = c6*4096 + tid*16;
    srcb[c6] = (n0 + o/384)*9600 + (o%384);
  }

  f32x4 acc[4][5] = {};
  short8 bfr0[10], bfr1[10], bfr2[10];

  // prologue: stage chunks 0,1; B for kt 0,1,2
  stageA(Xb, srcb, 0, &As[0][0], w);
  stageA(Xb, srcb, 1, &As[1][0], w);
  b_load(Wp, w, lane, 0, bfr0);
  b_load(Wp, w, lane, 1, bfr1);
  b_load(Wp, w, lane, 2, bfr2);

  #pragma unroll 1
  for(int c=0;c<25;++c){
    // wait: st(c) done, B(3c) done; leaves [B(3c+1), B(3c+2)] = 20 in flight
    asm volatile("s_waitcnt vmcnt(20)" ::: "memory");
    __builtin_amdgcn_sched_barrier(0);
    __builtin_amdgcn_s_barrier();
    __builtin_amdgcn_sched_barrier(0);
    {
      int cc = min(c+2, 24);
      stageA(Xb, srcb, cc, &As[(c+2)%3][0], w);
    }
    __builtin_amdgcn_sched_barrier(0);
    const ushort* Ab = &As[c%3][0];
    // j=0
    __builtin_amdgcn_s_setprio(1);
    do_mfma192(Ab, 0, lane, bfr0, acc);
    __builtin_amdgcn_s_setprio(0);
    b_load(Wp, w, lane, min(3*c+3,74), bfr0);
    __builtin_amdgcn_sched_barrier(0);
    asm volatile("s_waitcnt vmcnt(26)" ::: "memory");
    __builtin_amdgcn_sched_barrier(0);
    // j=1
    __builtin_amdgcn_s_setprio(1);
    do_mfma192(Ab, 1, lane, bfr1, acc);
    __builtin_amdgcn_s_setprio(0);
    b_load(Wp, w, lane, min(3*c+4,74), bfr1);
    __builtin_amdgcn_sched_barrier(0);
    asm volatile("s_waitcnt vmcnt(26)" ::: "memory");
    __builtin_amdgcn_sched_barrier(0);
    // j=2
    __builtin_amdgcn_s_setprio(1);
    do_mfma192(Ab, 2, lane, bfr2, acc);
    __builtin_amdgcn_s_setprio(0);
    b_load(Wp, w, lane, min(3*c+5,74), bfr2);
  }

  // epilogue
  int j = lane & 15, rg = (lane>>4)*4;
  #pragma unroll
  for(int ni=0;ni<5;++ni){
    int col16 = w*5 + ni;
    int l, part, lr;
    if(col16<2){l=0;part=col16;lr=0;}
    else if(col16<6){int c=col16-2;l=1;part=c>>1;lr=c&1;}
    else if(col16<12){int c=col16-6;l=2;part=(c>=3);lr=part?(c-3):c;}
    else {int c=col16-12;l=3;part=c>>2;lr=c&3;}
    float bv = 0.f;
    if(!(part==1 && lr==0)) bv = bp.p[l*2+part][lr*80 + p*16 + j];
    long base = 655360L*(l+1)*(l+part);
    int nst = (l+1)*80;
    long ioff = base + lr*80 + p*16 + j;
    #pragma unroll
    for(int mi=0;mi<4;++mi){
      int n = n0 + mi*16 + rg;
      #pragma unroll
      for(int r=0;r<4;++r)
        out[ioff + (long)(n+r)*nst] = acc[mi][ni][r] + bv;
    }
  }
}

// ---------------- fallback GEMM (R7, direct-from-x) — used if ws too small ---
__device__ __forceinline__ void a_load(const Ptrs8& xp, int p, int n0, int kt, int w, int lane, float4* v){
  int kb = kt*4 + w;
  int l2,partp,kx,t; decode_kb(kb,l2,partp,kx,t);
  const float* xb = xp.p[l2*2+partp];
  int nstr = 1200*(l2+1);
  const float* base = xb + (long)(n0 + (lane>>2))*nstr + (t*(l2+1)+kx)*80 + p*16 + (lane&3)*4;
  long step = (long)16*nstr;
  #pragma unroll
  for(int s=0;s<4;++s) v[s] = *(const float4*)(base + s*step);
}

__device__ __forceinline__ void a_store(ushort* As, int w, int lane, const float4* v){
  int rsub = lane>>2, c4 = (lane&3)*4;
  #pragma unroll
  for(int s=0;s<4;++s){
    int row = s*16 + rsub;
    int e = row*64 + ((w*16 + c4) ^ ((row&7)<<3));
    uint2 d;
    d.x = (uint)f2bf(v[s].x) | ((uint)f2bf(v[s].y)<<16);
    d.y = (uint)f2bf(v[s].z) | ((uint)f2bf(v[s].w)<<16);
    *(uint2*)(As + e) = d;
  }
}

__device__ __forceinline__ void do_mfma64(const ushort* As, int lane, const short8* b, f32x4 acc[4][5]){
  #pragma unroll
  for(int ks=0;ks<2;++ks){
    short8 af[4];
    #pragma unroll
    for(int mi=0;mi<4;++mi){
      int row = mi*16 + (lane&15);
      int e = row*64 + (((ks*32) + (lane>>4)*8) ^ ((row&7)<<3));
      af[mi] = *(const short8*)(As + e);
    }
    #pragma unroll
    for(int mi=0;mi<4;++mi)
      #pragma unroll
      for(int ni=0;ni<5;++ni)
        acc[mi][ni] = __builtin_amdgcn_mfma_f32_16x16x32_bf16(af[mi], b[ks*5+ni], acc[mi][ni], 0,0,0);
  }
}

__global__ __launch_bounds__(256,2) void gemm_direct(Ptrs8 xp, const ushort* __restrict__ Wb,
                                                     Ptrs8 bp, float* __restrict__ out){
  __shared__ ushort As[2][4096];
  const int tid = threadIdx.x;
  const int lane = tid & 63;
  const int w = tid >> 6;
  int orig = blockIdx.x;
  int x = orig & 7, q = orig >> 3;
  const int p = q % 5;
  const int nb = (q/5)*8 + x;
  const int n0 = nb*64;
  const ushort* Wp = Wb + (long)p*320*4800;

  f32x4 acc[4][5] = {};
  float4 av[4];
  short8 bfr[10];

  a_load(xp, p, n0, 0, w, lane, av);
  a_store(&As[0][0], w, lane, av);
  b_load(Wp, w, lane, 0, bfr);
  __syncthreads();

  int buf = 0;
  #pragma unroll 1
  for(int kt=0;kt<74;++kt){
    a_load(xp, p, n0, kt+1, w, lane, av);
    do_mfma64(&As[buf][0], lane, bfr, acc);
    b_load(Wp, w, lane, kt+1, bfr);
    a_store(&As[buf^1][0], w, lane, av);
    __syncthreads();
    buf ^= 1;
  }
  do_mfma64(&As[buf][0], lane, bfr, acc);

  int j = lane & 15, rg = (lane>>4)*4;
  #pragma unroll
  for(int ni=0;ni<5;++ni){
    int col16 = w*5 + ni;
    int l, part, lr;
    if(col16<2){l=0;part=col16;lr=0;}
    else if(col16<6){int c=col16-2;l=1;part=c>>1;lr=c&1;}
    else if(col16<12){int c=col16-6;l=2;part=(c>=3);lr=part?(c-3):c;}
    else {int c=col16-12;l=3;part=c>>2;lr=c&3;}
    float bv = 0.f;
    if(!(part==1 && lr==0)) bv = bp.p[l*2+part][lr*80 + p*16 + j];
    long base = 655360L*(l+1)*(l+part);
    int nst = (l+1)*80;
    long ioff = base + lr*80 + p*16 + j;
    #pragma unroll
    for(int mi=0;mi<4;++mi){
      int n = n0 + mi*16 + rg;
      #pragma unroll
      for(int r=0;r<4;++r)
        out[ioff + (long)(n+r)*nst] = acc[mi][ni][r] + bv;
    }
  }
}

extern "C" void kernel_launch(void* const* d_in, const int* in_sizes, int n_in,
                              void* d_out, int out_size, void* d_ws, size_t ws_size,
                              hipStream_t stream){
  Ptrs8 xp, wp, bp;
  for(int i=0;i<8;i++){
    xp.p[i] = (const float*)d_in[i];
    wp.p[i] = (const float*)d_in[8+i];
    bp.p[i] = (const float*)d_in[16+i];
  }
  float* G = (float*)d_ws;
  ushort* W = (ushort*)((char*)d_ws + 65536);
  g_kernel<<<dim3(1), dim3(576), 0, stream>>>(G);
  w_kernel<<<dim3(30000), dim3(256), 0, stream>>>(G, wp, W);
  const size_t need = 16777216ull + 5ull*8192*9600;
  if(ws_size >= need){
    ushort* Xp = (ushort*)((char*)d_ws + 16777216);
    pack_kernel<<<dim3(8192), dim3(256), 0, stream>>>(xp, Xp);
    gemm_xp<<<dim3(640), dim3(256), 0, stream>>>(Xp, W, bp, (float*)d_out);
  } else {
    gemm_direct<<<dim3(640), dim3(256), 0, stream>>>(xp, W, bp, (float*)d_out);
  }
}

// Round 9
// 662.782 us; speedup vs baseline: 1.0033x; 1.0033x over previous
//
#include <hip/hip_runtime.h>

#define PI_D 3.14159265358979323846

// Layouts
//  x[l2,part]: (8192, 15, l2+1, 5, 16) fp32  n-stride = 1200*(l2+1)
//  w[l1,part]: (l1+1, 15, 5, 16, 16)  fp32
//  b[l,part]:  (1, l+1, 5, 16)        fp32
//  out[l,part]:(8192, l+1, 5, 16) concat; base = 655360*(l+1)*(l+part)
// K (4800): l2{partp{kx{t{i16}}}}; kb offsets 0,30,90,180. col (320): l{part{lr{j16}}}
// ws: G[16384] f32 @0; W'[p][col][K] bf16 @64KB (15.36MB); Xp[p][n][K] bf16 @16MB (393MB)
// Xp slot-swizzle: 16-B slot s (=K>>3) stored at s ^ (n&7) within each 8-slot (64-K) group.

typedef __attribute__((ext_vector_type(8))) short short8;
typedef __attribute__((ext_vector_type(4))) float f32x4;

struct Ptrs8 { const float* p[8]; };

#define SB() __builtin_amdgcn_sched_barrier(0)

__device__ __forceinline__ ushort f2bf(float x){
  uint u = __float_as_uint(x);
  return (ushort)((u + 0x7fffu + ((u>>16)&1u)) >> 16);
}

__device__ __forceinline__ void gload16(const void* g, ushort* l){
  __builtin_amdgcn_global_load_lds((const __attribute__((address_space(1))) void*)g,
                                   (__attribute__((address_space(3))) void*)l, 16, 0, 0);
}

__device__ __forceinline__ double dfact(int n){ double r=1.0; for(int i=2;i<=n;++i) r*=(double)i; return r; }

__device__ double cg_coef(int j1,int m1,int j2,int m2,int j3,int m3){
  if(m1+m2!=m3) return 0.0;
  if(j3<abs(j1-j2)||j3>j1+j2) return 0.0;
  if(abs(m1)>j1||abs(m2)>j2||abs(m3)>j3) return 0.0;
  double pre = sqrt((2.0*j3+1.0)*dfact(j3+j1-j2)*dfact(j3-j1+j2)*dfact(j1+j2-j3)/dfact(j1+j2+j3+1));
  pre *= sqrt(dfact(j3+m3)*dfact(j3-m3)*dfact(j1-m1)*dfact(j1+m1)*dfact(j2-m2)*dfact(j2+m2));
  int kmin = max(0,max(j2-j3-m1,j1-j3+m2));
  int kmax = min(j1+j2-j3,min(j1-m1,j2+m2));
  double s=0.0;
  for(int k=kmin;k<=kmax;++k){
    double d = dfact(k)*dfact(j1+j2-j3-k)*dfact(j1-m1-k)*dfact(j2+m2-k)*dfact(j3-j2+m1+k)*dfact(j3-j1-m2+k);
    s += ((k&1)?-1.0:1.0)/d;
  }
  return pre*s;
}

__device__ __forceinline__ int gidx(int l,int l2,int combo,int lr,int kx,int l1,int m){
  return ((((((l*4+l2)*4+combo)*4+lr)*4+kx)*4+l1)*4+m);
}

__global__ void g_kernel(float* __restrict__ G){
  int tid = threadIdx.x;
  for(int e=tid;e<16384;e+=blockDim.x) G[e]=0.0f;
  __syncthreads();
  int trip = tid >> 4;
  int sub  = tid & 15;
  int lr = sub >> 2, m = sub & 3;
  int idx=0;
  for(int l=0;l<4;l++)for(int l1=0;l1<4;l1++){
    int lo=abs(l-l1), hi=min(3,l+l1);
    for(int l2=lo;l2<=hi;l2++){
      if(idx==trip && lr<=l && m<=l1){
        double c = 8.0*PI_D*PI_D/(2.0*l1+1.0)
                 * sqrt((2.0*l+1.0)*(2.0*l1+1.0)/(4.0*PI_D*(2.0*l2+1.0)))
                 * cg_coef(l,0,l1,0,l2,0);
        if(lr+m<=l2){
          float f = (float)(c * cg_coef(l,lr,l1,m,l2,lr+m) * ((m&1)?-1.0:1.0));
          G[gidx(l,l2,0,lr,lr+m,l1,m)] += f;
          G[gidx(l,l2,1,lr,lr+m,l1,m)] -= f;
          G[gidx(l,l2,2,lr,lr+m,l1,m)] += f;
          G[gidx(l,l2,3,lr,lr+m,l1,m)] += f;
        }
        if(m>0 && abs(lr-m)<=l2){
          if(lr-m>=0){
            float f = (float)(c * cg_coef(l,lr,l1,-m,l2,lr-m) * ((l1&1)?-1.0:1.0));
            G[gidx(l,l2,0,lr,lr-m,l1,m)] += f;
            G[gidx(l,l2,1,lr,lr-m,l1,m)] += f;
            G[gidx(l,l2,2,lr,lr-m,l1,m)] -= f;
            G[gidx(l,l2,3,lr,lr-m,l1,m)] += f;
          } else {
            float f = (float)(c * (((m-lr)&1)?-1.0:1.0) * (((l1+l2)&1)?-1.0:1.0)
                              * cg_coef(l,lr,l1,-m,l2,lr-m));
            G[gidx(l,l2,0,lr,m-lr,l1,m)] += f;
            G[gidx(l,l2,1,lr,m-lr,l1,m)] -= f;
            G[gidx(l,l2,2,lr,m-lr,l1,m)] -= f;
            G[gidx(l,l2,3,lr,m-lr,l1,m)] -= f;
          }
        }
      }
      idx++;
    }
  }
}

__device__ __forceinline__ void decode_kb(int kb,int& l2,int& partp,int& kx,int& t){
  int kbo;
  if(kb<30){l2=0;kbo=0;} else if(kb<90){l2=1;kbo=30;} else if(kb<180){l2=2;kbo=90;} else {l2=3;kbo=180;}
  int rem = kb-kbo;
  int per = (l2+1)*15;
  partp = rem/per;
  int q = rem%per;
  kx = q/15; t = q%15;
}

__device__ __forceinline__ void decode_col(int col,int& l,int& part,int& lr,int& j){
  int co;
  if(col<32){l=0;co=0;} else if(col<96){l=1;co=32;} else if(col<192){l=2;co=96;} else {l=3;co=192;}
  int cr = col-co; int per=(l+1)*16;
  part = cr/per; int q = cr%per; lr = q>>4; j = q&15;
}

// W'[p][col][K] bf16
__global__ void w_kernel(const float* __restrict__ G, Ptrs8 wp, ushort* __restrict__ W){
  long e = (long)blockIdx.x*256 + threadIdx.x;
  if(e >= 5L*320*4800) return;
  int K = (int)(e%4800); long r = e/4800; int col = (int)(r%320); int p = (int)(r/320);
  int i = K & 15; int kb = K >> 4;
  int l2,partp,kx,t; decode_kb(kb,l2,partp,kx,t);
  int l,part,lr,j; decode_col(col,l,part,lr,j);
  int combo = (part==0) ? (partp==0?0:1) : (partp==0?2:3);
  int wpart = (combo==0||combo==3)?0:1;
  int mstart = wpart?1:0;
  int woff = t*1280 + p*256 + i*16 + j;
  float acc=0.f;
  for(int l1=0;l1<4;l1++){
    const float* wptr = wp.p[l1*2+wpart];
    int gb = ((((l*4+l2)*4+combo)*4+lr)*4+kx)*16 + l1*4;
    for(int m=mstart;m<=l1;m++){
      float g = G[gb+m];
      if(g!=0.f) acc += g * wptr[m*19200 + woff];
    }
  }
  W[e] = f2bf(acc);
}

// ---------------- pack: x (fp32, n-major) -> Xp[p][n][K] bf16, slot-swizzled --
__global__ __launch_bounds__(256) void pack_kernel(Ptrs8 xp, ushort* __restrict__ Xp){
  __shared__ ushort L[5*4816];
  const int tid = threadIdx.x;
  const int n = blockIdx.x;
  const int nsw = (n & 7) << 3;
  #pragma unroll
  for(int a=0;a<8;a++){
    const int l2 = a>>1, partp = a&1;
    const int kbo = (l2==0)?0:(l2==1)?30:(l2==2)?90:180;
    const int kbase = kbo + partp*15*(l2+1);
    const float* row = xp.p[a] + (long)n*1200*(l2+1);
    const int nf4 = 300*(l2+1);
    for(int u=tid; u<nf4; u+=256){
      float4 v = ((const float4*)row)[u];
      int f = u*4;
      int i = f & 15;
      int r = f >> 4;
      int p = r % 5;
      int tk = r / 5;
      int kx = tk % (l2+1);
      int t  = tk / (l2+1);
      int K = (kbase + kx*15 + t)*16 + i;
      int idx = p*4816 + ((((K>>3)*8) ^ nsw)) + (K&7);
      uint2 d;
      d.x = (uint)f2bf(v.x) | ((uint)f2bf(v.y)<<16);
      d.y = (uint)f2bf(v.z) | ((uint)f2bf(v.w)<<16);
      *(uint2*)(&L[idx]) = d;
    }
  }
  __syncthreads();
  for(int u=tid; u<3000; u+=256){
    int p = u/600, b = u - p*600;
    const uint4 s = *(const uint4*)(&L[p*4816 + b*8]);
    *(uint4*)((char*)Xp + ((long)p*8192 + n)*9600 + b*16) = s;
  }
}

// ---------------- GEMM (packed, T3/T4 discipline) ---------------------------
// 64-row x 320-col tile, 4 waves (80 cols each), grid 640 (XCD p-chunked).
// A: Xp via global_load_lds into 3 x 8KB LDS buffers; stage(kt+2) issued each
// iter -> 2 iters of HBM cover. Constant counted wait vmcnt(12) (never 0!),
// NO "memory" clobber on waitcnt asm (that was R4/R5/R8's hidden full-drain).
// B: reg ping-pong, distance 1 iter (L2). One barrier per iter.

__device__ __forceinline__ void b_load(const ushort* Wp,int w,int lane,int kt,short8* b){
  const ushort* q = Wp + (long)(w*80 + (lane&15))*4800 + kt*64 + ((lane>>4)*8);
  #pragma unroll
  for(int ks=0;ks<2;++ks)
    #pragma unroll
    for(int ni=0;ni<5;++ni)
      b[ks*5+ni] = *(const short8*)(q + (long)ni*16*4800 + ks*32);
}

__device__ __forceinline__ void do_mfma_v2(const ushort* A,int lane,const short8* b,f32x4 acc[4][5]){
  #pragma unroll
  for(int ks=0;ks<2;++ks){
    short8 af[4];
    #pragma unroll
    for(int mi=0;mi<4;++mi){
      int nn = mi*16 + (lane&15);
      int u = nn*64 + ((ks*32 + ((lane>>4)<<3)) ^ ((nn&7)<<3));
      af[mi] = *(const short8*)(A + u);
    }
    #pragma unroll
    for(int mi=0;mi<4;++mi)
      #pragma unroll
      for(int ni=0;ni<5;++ni)
        acc[mi][ni] = __builtin_amdgcn_mfma_f32_16x16x32_bf16(af[mi], b[ks*5+ni], acc[mi][ni], 0,0,0);
  }
}

__device__ __forceinline__ void stage2(const char* s0,const char* s1,ushort* buf,int w,int kt){
  gload16(s0 + kt*128, buf + w*512);
  gload16(s1 + kt*128, buf + 2048 + w*512);
}

__global__ __launch_bounds__(256,2) void gemm_xp(const ushort* __restrict__ Xp,
                                                 const ushort* __restrict__ Wb,
                                                 Ptrs8 bp, float* __restrict__ out){
  __shared__ ushort As[3][4096];
  const int tid = threadIdx.x;
  const int lane = tid & 63;
  const int w = tid >> 6;
  int orig = blockIdx.x;
  int wg = (orig & 7)*80 + (orig >> 3);   // XCD-chunked: ~one p-slice per XCD
  const int p = wg / 128;
  const int nb = wg % 128;
  const int n0 = nb*64;
  const ushort* Wp = Wb + (long)p*320*4800;
  const char* Xb = (const char*)Xp + (long)p*8192*9600;
  // per-thread A staging sources: rows tid>>3 (+0) and (+32), col (tid&7)*16 B
  const char* srcA = Xb + (long)(n0 + (tid>>3))*9600 + (tid&7)*16;
  const char* srcB = srcA + 32*9600;

  f32x4 acc[4][5] = {};
  short8 bfA[10], bfB[10];

  // prologue: stage kt 0,1; B(0)
  stage2(srcA, srcB, &As[0][0], w, 0);
  stage2(srcA, srcB, &As[1][0], w, 1);
  b_load(Wp, w, lane, 0, bfA);
  // ---- kt = 0 (wait count 10: drains s0,s1,B0; leaves B1) ----
  b_load(Wp, w, lane, 1, bfB); SB();
  asm volatile("s_waitcnt vmcnt(10)");
  asm volatile("s_waitcnt lgkmcnt(0)"); SB();
  __builtin_amdgcn_s_barrier(); SB();
  stage2(srcA, srcB, &As[2][0], w, 2); SB();
  __builtin_amdgcn_s_setprio(1);
  do_mfma_v2(&As[0][0], lane, bfA, acc);
  __builtin_amdgcn_s_setprio(0);

  // steady state: entering kt, outstanding = [s(kt)2, B(kt)10, s(kt+1)2];
  // +B(kt+1)10 -> 24; vmcnt(12) drains s(kt)+B(kt); stage(kt+2) after barrier.
#define STEPX(kt, bIn, bOut) do { \
    b_load(Wp, w, lane, min((kt)+1,74), bOut); SB(); \
    asm volatile("s_waitcnt vmcnt(12)"); \
    asm volatile("s_waitcnt lgkmcnt(0)"); SB(); \
    __builtin_amdgcn_s_barrier(); SB(); \
    stage2(srcA, srcB, &As[((kt)+2)%3][0], w, min((kt)+2,74)); SB(); \
    __builtin_amdgcn_s_setprio(1); \
    do_mfma_v2(&As[(kt)%3][0], lane, bIn, acc); \
    __builtin_amdgcn_s_setprio(0); \
  } while(0)

  #pragma unroll 1
  for(int kt=1; kt<75; kt+=2){
    STEPX(kt,   bfB, bfA);
    STEPX(kt+1, bfA, bfB);
  }
#undef STEPX

  // epilogue
  int j = lane & 15, rg = (lane>>4)*4;
  #pragma unroll
  for(int ni=0;ni<5;++ni){
    int col16 = w*5 + ni;
    int l, part, lr;
    if(col16<2){l=0;part=col16;lr=0;}
    else if(col16<6){int c=col16-2;l=1;part=c>>1;lr=c&1;}
    else if(col16<12){int c=col16-6;l=2;part=(c>=3);lr=part?(c-3):c;}
    else {int c=col16-12;l=3;part=c>>2;lr=c&3;}
    float bv = 0.f;
    if(!(part==1 && lr==0)) bv = bp.p[l*2+part][lr*80 + p*16 + j];
    long base = 655360L*(l+1)*(l+part);
    int nst = (l+1)*80;
    long ioff = base + lr*80 + p*16 + j;
    #pragma unroll
    for(int mi=0;mi<4;++mi){
      int n = n0 + mi*16 + rg;
      #pragma unroll
      for(int r=0;r<4;++r)
        out[ioff + (long)(n+r)*nst] = acc[mi][ni][r] + bv;
    }
  }
}

// ---------------- fallback GEMM (direct-from-x, R7) -------------------------
__device__ __forceinline__ void a_load(const Ptrs8& xp, int p, int n0, int kt, int w, int lane, float4* v){
  int kb = kt*4 + w;
  int l2,partp,kx,t; decode_kb(kb,l2,partp,kx,t);
  const float* xb = xp.p[l2*2+partp];
  int nstr = 1200*(l2+1);
  const float* base = xb + (long)(n0 + (lane>>2))*nstr + (t*(l2+1)+kx)*80 + p*16 + (lane&3)*4;
  long step = (long)16*nstr;
  #pragma unroll
  for(int s=0;s<4;++s) v[s] = *(const float4*)(base + s*step);
}

__device__ __forceinline__ void a_store(ushort* As, int w, int lane, const float4* v){
  int rsub = lane>>2, c4 = (lane&3)*4;
  #pragma unroll
  for(int s=0;s<4;++s){
    int row = s*16 + rsub;
    int e = row*64 + ((w*16 + c4) ^ ((row&7)<<3));
    uint2 d;
    d.x = (uint)f2bf(v[s].x) | ((uint)f2bf(v[s].y)<<16);
    d.y = (uint)f2bf(v[s].z) | ((uint)f2bf(v[s].w)<<16);
    *(uint2*)(As + e) = d;
  }
}

__device__ __forceinline__ void do_mfma64(const ushort* As, int lane, const short8* b, f32x4 acc[4][5]){
  #pragma unroll
  for(int ks=0;ks<2;++ks){
    short8 af[4];
    #pragma unroll
    for(int mi=0;mi<4;++mi){
      int row = mi*16 + (lane&15);
      int e = row*64 + (((ks*32) + (lane>>4)*8) ^ ((row&7)<<3));
      af[mi] = *(const short8*)(As + e);
    }
    #pragma unroll
    for(int mi=0;mi<4;++mi)
      #pragma unroll
      for(int ni=0;ni<5;++ni)
        acc[mi][ni] = __builtin_amdgcn_mfma_f32_16x16x32_bf16(af[mi], b[ks*5+ni], acc[mi][ni], 0,0,0);
  }
}

__global__ __launch_bounds__(256,2) void gemm_direct(Ptrs8 xp, const ushort* __restrict__ Wb,
                                                     Ptrs8 bp, float* __restrict__ out){
  __shared__ ushort As[2][4096];
  const int tid = threadIdx.x;
  const int lane = tid & 63;
  const int w = tid >> 6;
  int orig = blockIdx.x;
  int x = orig & 7, q = orig >> 3;
  const int p = q % 5;
  const int nb = (q/5)*8 + x;
  const int n0 = nb*64;
  const ushort* Wp = Wb + (long)p*320*4800;

  f32x4 acc[4][5] = {};
  float4 av[4];
  short8 bfr[10];

  a_load(xp, p, n0, 0, w, lane, av);
  a_store(&As[0][0], w, lane, av);
  b_load(Wp, w, lane, 0, bfr);
  __syncthreads();

  int buf = 0;
  #pragma unroll 1
  for(int kt=0;kt<74;++kt){
    a_load(xp, p, n0, kt+1, w, lane, av);
    do_mfma64(&As[buf][0], lane, bfr, acc);
    b_load(Wp, w, lane, kt+1, bfr);
    a_store(&As[buf^1][0], w, lane, av);
    __syncthreads();
    buf ^= 1;
  }
  do_mfma64(&As[buf][0], lane, bfr, acc);

  int j = lane & 15, rg = (lane>>4)*4;
  #pragma unroll
  for(int ni=0;ni<5;++ni){
    int col16 = w*5 + ni;
    int l, part, lr;
    if(col16<2){l=0;part=col16;lr=0;}
    else if(col16<6){int c=col16-2;l=1;part=c>>1;lr=c&1;}
    else if(col16<12){int c=col16-6;l=2;part=(c>=3);lr=part?(c-3):c;}
    else {int c=col16-12;l=3;part=c>>2;lr=c&3;}
    float bv = 0.f;
    if(!(part==1 && lr==0)) bv = bp.p[l*2+part][lr*80 + p*16 + j];
    long base = 655360L*(l+1)*(l+part);
    int nst = (l+1)*80;
    long ioff = base + lr*80 + p*16 + j;
    #pragma unroll
    for(int mi=0;mi<4;++mi){
      int n = n0 + mi*16 + rg;
      #pragma unroll
      for(int r=0;r<4;++r)
        out[ioff + (long)(n+r)*nst] = acc[mi][ni][r] + bv;
    }
  }
}

extern "C" void kernel_launch(void* const* d_in, const int* in_sizes, int n_in,
                              void* d_out, int out_size, void* d_ws, size_t ws_size,
                              hipStream_t stream){
  Ptrs8 xp, wp, bp;
  for(int i=0;i<8;i++){
    xp.p[i] = (const float*)d_in[i];
    wp.p[i] = (const float*)d_in[8+i];
    bp.p[i] = (const float*)d_in[16+i];
  }
  float* G = (float*)d_ws;
  ushort* W = (ushort*)((char*)d_ws + 65536);
  g_kernel<<<dim3(1), dim3(576), 0, stream>>>(G);
  w_kernel<<<dim3(30000), dim3(256), 0, stream>>>(G, wp, W);
  const size_t need = 16777216ull + 5ull*8192*9600;
  if(ws_size >= need){
    ushort* Xp = (ushort*)((char*)d_ws + 16777216);
    pack_kernel<<<dim3(8192), dim3(256), 0, stream>>>(xp, Xp);
    gemm_xp<<<dim3(640), dim3(256), 0, stream>>>(Xp, W, bp, (float*)d_out);
  } else {
    gemm_direct<<<dim3(640), dim3(256), 0, stream>>>(xp, W, bp, (float*)d_out);
  }
}

// Round 10
// 647.353 us; speedup vs baseline: 1.0272x; 1.0238x over previous
//
#include <hip/hip_runtime.h>

#define PI_D 3.14159265358979323846

// Layouts
//  x[l2,part]: (8192, 15, l2+1, 5, 16) fp32  n-stride = 1200*(l2+1)
//  w[l1,part]: (l1+1, 15, 5, 16, 16)  fp32
//  b[l,part]:  (1, l+1, 5, 16)        fp32
//  out[l,part]:(8192, l+1, 5, 16) concat; base = 655360*(l+1)*(l+part)
// K (4800): l2{partp{kx{t{i16}}}}; kb offsets 0,30,90,180. col (320): l{part{lr{j16}}}
// ws: G[16384] f32 @0; W'[p][col][K] bf16 @64KB (15.36MB); Xp[p][n][K] bf16 @16MB (393MB)
// Xp slot-swizzle: 16-B slot s (=K>>3) stored at s ^ (n&7) within each 8-slot (64-K) group.

typedef __attribute__((ext_vector_type(8))) short short8;
typedef __attribute__((ext_vector_type(4))) float f32x4;

struct Ptrs8 { const float* p[8]; };

__device__ __forceinline__ ushort f2bf(float x){
  uint u = __float_as_uint(x);
  return (ushort)((u + 0x7fffu + ((u>>16)&1u)) >> 16);
}

__device__ __forceinline__ double dfact(int n){ double r=1.0; for(int i=2;i<=n;++i) r*=(double)i; return r; }

__device__ double cg_coef(int j1,int m1,int j2,int m2,int j3,int m3){
  if(m1+m2!=m3) return 0.0;
  if(j3<abs(j1-j2)||j3>j1+j2) return 0.0;
  if(abs(m1)>j1||abs(m2)>j2||abs(m3)>j3) return 0.0;
  double pre = sqrt((2.0*j3+1.0)*dfact(j3+j1-j2)*dfact(j3-j1+j2)*dfact(j1+j2-j3)/dfact(j1+j2+j3+1));
  pre *= sqrt(dfact(j3+m3)*dfact(j3-m3)*dfact(j1-m1)*dfact(j1+m1)*dfact(j2-m2)*dfact(j2+m2));
  int kmin = max(0,max(j2-j3-m1,j1-j3+m2));
  int kmax = min(j1+j2-j3,min(j1-m1,j2+m2));
  double s=0.0;
  for(int k=kmin;k<=kmax;++k){
    double d = dfact(k)*dfact(j1+j2-j3-k)*dfact(j1-m1-k)*dfact(j2+m2-k)*dfact(j3-j2+m1+k)*dfact(j3-j1-m2+k);
    s += ((k&1)?-1.0:1.0)/d;
  }
  return pre*s;
}

__device__ __forceinline__ int gidx(int l,int l2,int combo,int lr,int kx,int l1,int m){
  return ((((((l*4+l2)*4+combo)*4+lr)*4+kx)*4+l1)*4+m);
}

__global__ void g_kernel(float* __restrict__ G){
  int tid = threadIdx.x;
  for(int e=tid;e<16384;e+=blockDim.x) G[e]=0.0f;
  __syncthreads();
  int trip = tid >> 4;
  int sub  = tid & 15;
  int lr = sub >> 2, m = sub & 3;
  int idx=0;
  for(int l=0;l<4;l++)for(int l1=0;l1<4;l1++){
    int lo=abs(l-l1), hi=min(3,l+l1);
    for(int l2=lo;l2<=hi;l2++){
      if(idx==trip && lr<=l && m<=l1){
        double c = 8.0*PI_D*PI_D/(2.0*l1+1.0)
                 * sqrt((2.0*l+1.0)*(2.0*l1+1.0)/(4.0*PI_D*(2.0*l2+1.0)))
                 * cg_coef(l,0,l1,0,l2,0);
        if(lr+m<=l2){
          float f = (float)(c * cg_coef(l,lr,l1,m,l2,lr+m) * ((m&1)?-1.0:1.0));
          G[gidx(l,l2,0,lr,lr+m,l1,m)] += f;
          G[gidx(l,l2,1,lr,lr+m,l1,m)] -= f;
          G[gidx(l,l2,2,lr,lr+m,l1,m)] += f;
          G[gidx(l,l2,3,lr,lr+m,l1,m)] += f;
        }
        if(m>0 && abs(lr-m)<=l2){
          if(lr-m>=0){
            float f = (float)(c * cg_coef(l,lr,l1,-m,l2,lr-m) * ((l1&1)?-1.0:1.0));
            G[gidx(l,l2,0,lr,lr-m,l1,m)] += f;
            G[gidx(l,l2,1,lr,lr-m,l1,m)] += f;
            G[gidx(l,l2,2,lr,lr-m,l1,m)] -= f;
            G[gidx(l,l2,3,lr,lr-m,l1,m)] += f;
          } else {
            float f = (float)(c * (((m-lr)&1)?-1.0:1.0) * (((l1+l2)&1)?-1.0:1.0)
                              * cg_coef(l,lr,l1,-m,l2,lr-m));
            G[gidx(l,l2,0,lr,m-lr,l1,m)] += f;
            G[gidx(l,l2,1,lr,m-lr,l1,m)] -= f;
            G[gidx(l,l2,2,lr,m-lr,l1,m)] -= f;
            G[gidx(l,l2,3,lr,m-lr,l1,m)] -= f;
          }
        }
      }
      idx++;
    }
  }
}

__device__ __forceinline__ void decode_kb(int kb,int& l2,int& partp,int& kx,int& t){
  int kbo;
  if(kb<30){l2=0;kbo=0;} else if(kb<90){l2=1;kbo=30;} else if(kb<180){l2=2;kbo=90;} else {l2=3;kbo=180;}
  int rem = kb-kbo;
  int per = (l2+1)*15;
  partp = rem/per;
  int q = rem%per;
  kx = q/15; t = q%15;
}

__device__ __forceinline__ void decode_col(int col,int& l,int& part,int& lr,int& j){
  int co;
  if(col<32){l=0;co=0;} else if(col<96){l=1;co=32;} else if(col<192){l=2;co=96;} else {l=3;co=192;}
  int cr = col-co; int per=(l+1)*16;
  part = cr/per; int q = cr%per; lr = q>>4; j = q&15;
}

// W'[p][col][K] bf16
__global__ void w_kernel(const float* __restrict__ G, Ptrs8 wp, ushort* __restrict__ W){
  long e = (long)blockIdx.x*256 + threadIdx.x;
  if(e >= 5L*320*4800) return;
  int K = (int)(e%4800); long r = e/4800; int col = (int)(r%320); int p = (int)(r/320);
  int i = K & 15; int kb = K >> 4;
  int l2,partp,kx,t; decode_kb(kb,l2,partp,kx,t);
  int l,part,lr,j; decode_col(col,l,part,lr,j);
  int combo = (part==0) ? (partp==0?0:1) : (partp==0?2:3);
  int wpart = (combo==0||combo==3)?0:1;
  int mstart = wpart?1:0;
  int woff = t*1280 + p*256 + i*16 + j;
  float acc=0.f;
  for(int l1=0;l1<4;l1++){
    const float* wptr = wp.p[l1*2+wpart];
    int gb = ((((l*4+l2)*4+combo)*4+lr)*4+kx)*16 + l1*4;
    for(int m=mstart;m<=l1;m++){
      float g = G[gb+m];
      if(g!=0.f) acc += g * wptr[m*19200 + woff];
    }
  }
  W[e] = f2bf(acc);
}

// ---------------- pack: x (fp32, n-major) -> Xp[p][n][K] bf16, slot-swizzled --
__global__ __launch_bounds__(512) void pack_kernel(Ptrs8 xp, ushort* __restrict__ Xp){
  __shared__ ushort L[5*4816];
  const int tid = threadIdx.x;
  const int n = blockIdx.x;
  const int nsw = (n & 7) << 3;
  #pragma unroll
  for(int a=0;a<8;a++){
    const int l2 = a>>1, partp = a&1;
    const int kbo = (l2==0)?0:(l2==1)?30:(l2==2)?90:180;
    const int kbase = kbo + partp*15*(l2+1);
    const float* row = xp.p[a] + (long)n*1200*(l2+1);
    const int nf4 = 300*(l2+1);
    for(int u=tid; u<nf4; u+=512){
      float4 v = ((const float4*)row)[u];
      int f = u*4;
      int i = f & 15;
      int r = f >> 4;
      int p = r % 5;
      int tk = r / 5;
      int kx = tk % (l2+1);
      int t  = tk / (l2+1);
      int K = (kbase + kx*15 + t)*16 + i;
      int idx = p*4816 + ((((K>>3)*8) ^ nsw)) + (K&7);
      uint2 d;
      d.x = (uint)f2bf(v.x) | ((uint)f2bf(v.y)<<16);
      d.y = (uint)f2bf(v.z) | ((uint)f2bf(v.w)<<16);
      *(uint2*)(&L[idx]) = d;
    }
  }
  __syncthreads();
  for(int u=tid; u<3000; u+=512){
    int p = u/600, b = u - p*600;
    const uint4 s = *(const uint4*)(&L[p*4816 + b*8]);
    *(uint4*)((char*)Xp + ((long)p*8192 + n)*9600 + b*16) = s;
  }
}

// ---------------- GEMM (packed, reg-staged R2 schedule) ----------------------
// 64-row x 320-col tile, 4 waves (80 cols each), grid 640 (XCD p-chunked).
// A: contiguous bf16 from Xp -> VGPR (2 x b128/thread) -> linear ds_write
// (swizzle baked in Xp). NO global_load_lds => no compiler vmcnt drains before
// ds_read; lgkm waits are precise. __syncthreads per iter (R2-proven).
// B: reg from L2, prefetch distance 1 iter.

__device__ __forceinline__ void b_load(const ushort* Wp,int w,int lane,int kt,short8* b){
  const ushort* q = Wp + (long)(w*80 + (lane&15))*4800 + kt*64 + ((lane>>4)*8);
  #pragma unroll
  for(int ks=0;ks<2;++ks)
    #pragma unroll
    for(int ni=0;ni<5;++ni)
      b[ks*5+ni] = *(const short8*)(q + (long)ni*16*4800 + ks*32);
}

__device__ __forceinline__ void do_mfma_v2(const ushort* A,int lane,const short8* b,f32x4 acc[4][5]){
  #pragma unroll
  for(int ks=0;ks<2;++ks){
    short8 af[4];
    #pragma unroll
    for(int mi=0;mi<4;++mi){
      int nn = mi*16 + (lane&15);
      int u = nn*64 + ((ks*32 + ((lane>>4)<<3)) ^ ((nn&7)<<3));
      af[mi] = *(const short8*)(A + u);
    }
    #pragma unroll
    for(int mi=0;mi<4;++mi)
      #pragma unroll
      for(int ni=0;ni<5;++ni)
        acc[mi][ni] = __builtin_amdgcn_mfma_f32_16x16x32_bf16(af[mi], b[ks*5+ni], acc[mi][ni], 0,0,0);
  }
}

__global__ __launch_bounds__(256,2) void gemm_xp2(const ushort* __restrict__ Xp,
                                                  const ushort* __restrict__ Wb,
                                                  Ptrs8 bp, float* __restrict__ out){
  __shared__ ushort As[2][4096];
  const int tid = threadIdx.x;
  const int lane = tid & 63;
  const int w = tid >> 6;
  int orig = blockIdx.x;
  int wg = (orig & 7)*80 + (orig >> 3);   // XCD-chunked: ~one p-slice per XCD
  const int p = wg / 128;
  const int nb = wg % 128;
  const int n0 = nb*64;
  const ushort* Wp = Wb + (long)p*320*4800;
  const char* Xb = (const char*)Xp + (long)p*8192*9600;
  // per-thread A source: rows n0+(tid>>3) and +32, 16-B chunk (tid&7), +kt*128
  const char* srcA = Xb + (long)(n0 + (tid>>3))*9600 + (tid&7)*16;
  const char* srcB = srcA + 32*9600;
  // linear LDS dest (ushort idx)
  const int dA = (tid>>3)*64 + (tid&7)*8;
  const int dB = dA + 32*64;

  f32x4 acc[4][5] = {};
  uint4 avA, avB;
  short8 bfr[10];

  // prologue: tile 0 -> LDS; B(0)
  avA = *(const uint4*)(srcA);
  avB = *(const uint4*)(srcB);
  *(uint4*)(&As[0][dA]) = avA;
  *(uint4*)(&As[0][dB]) = avB;
  b_load(Wp, w, lane, 0, bfr);
  __syncthreads();

  int buf = 0;
  #pragma unroll 1
  for(int kt=0;kt<74;++kt){
    avA = *(const uint4*)(srcA + (kt+1)*128);   // A(kt+1) -> regs (L3/HBM)
    avB = *(const uint4*)(srcB + (kt+1)*128);
    do_mfma_v2(&As[buf][0], lane, bfr, acc);    // compute tile kt
    b_load(Wp, w, lane, kt+1, bfr);             // B(kt+1) from L2
    *(uint4*)(&As[buf^1][dA]) = avA;            // A(kt+1) -> LDS
    *(uint4*)(&As[buf^1][dB]) = avB;
    __syncthreads();
    buf ^= 1;
  }
  do_mfma_v2(&As[buf][0], lane, bfr, acc);

  // epilogue
  int j = lane & 15, rg = (lane>>4)*4;
  #pragma unroll
  for(int ni=0;ni<5;++ni){
    int col16 = w*5 + ni;
    int l, part, lr;
    if(col16<2){l=0;part=col16;lr=0;}
    else if(col16<6){int c=col16-2;l=1;part=c>>1;lr=c&1;}
    else if(col16<12){int c=col16-6;l=2;part=(c>=3);lr=part?(c-3):c;}
    else {int c=col16-12;l=3;part=c>>2;lr=c&3;}
    float bv = 0.f;
    if(!(part==1 && lr==0)) bv = bp.p[l*2+part][lr*80 + p*16 + j];
    long base = 655360L*(l+1)*(l+part);
    int nst = (l+1)*80;
    long ioff = base + lr*80 + p*16 + j;
    #pragma unroll
    for(int mi=0;mi<4;++mi){
      int n = n0 + mi*16 + rg;
      #pragma unroll
      for(int r=0;r<4;++r)
        out[ioff + (long)(n+r)*nst] = acc[mi][ni][r] + bv;
    }
  }
}

// ---------------- fallback GEMM (direct-from-x, R7) -------------------------
__device__ __forceinline__ void a_load(const Ptrs8& xp, int p, int n0, int kt, int w, int lane, float4* v){
  int kb = kt*4 + w;
  int l2,partp,kx,t; decode_kb(kb,l2,partp,kx,t);
  const float* xb = xp.p[l2*2+partp];
  int nstr = 1200*(l2+1);
  const float* base = xb + (long)(n0 + (lane>>2))*nstr + (t*(l2+1)+kx)*80 + p*16 + (lane&3)*4;
  long step = (long)16*nstr;
  #pragma unroll
  for(int s=0;s<4;++s) v[s] = *(const float4*)(base + s*step);
}

__device__ __forceinline__ void a_store(ushort* As, int w, int lane, const float4* v){
  int rsub = lane>>2, c4 = (lane&3)*4;
  #pragma unroll
  for(int s=0;s<4;++s){
    int row = s*16 + rsub;
    int e = row*64 + ((w*16 + c4) ^ ((row&7)<<3));
    uint2 d;
    d.x = (uint)f2bf(v[s].x) | ((uint)f2bf(v[s].y)<<16);
    d.y = (uint)f2bf(v[s].z) | ((uint)f2bf(v[s].w)<<16);
    *(uint2*)(As + e) = d;
  }
}

__device__ __forceinline__ void do_mfma64(const ushort* As, int lane, const short8* b, f32x4 acc[4][5]){
  #pragma unroll
  for(int ks=0;ks<2;++ks){
    short8 af[4];
    #pragma unroll
    for(int mi=0;mi<4;++mi){
      int row = mi*16 + (lane&15);
      int e = row*64 + (((ks*32) + (lane>>4)*8) ^ ((row&7)<<3));
      af[mi] = *(const short8*)(As + e);
    }
    #pragma unroll
    for(int mi=0;mi<4;++mi)
      #pragma unroll
      for(int ni=0;ni<5;++ni)
        acc[mi][ni] = __builtin_amdgcn_mfma_f32_16x16x32_bf16(af[mi], b[ks*5+ni], acc[mi][ni], 0,0,0);
  }
}

__global__ __launch_bounds__(256,2) void gemm_direct(Ptrs8 xp, const ushort* __restrict__ Wb,
                                                     Ptrs8 bp, float* __restrict__ out){
  __shared__ ushort As[2][4096];
  const int tid = threadIdx.x;
  const int lane = tid & 63;
  const int w = tid >> 6;
  int orig = blockIdx.x;
  int x = orig & 7, q = orig >> 3;
  const int p = q % 5;
  const int nb = (q/5)*8 + x;
  const int n0 = nb*64;
  const ushort* Wp = Wb + (long)p*320*4800;

  f32x4 acc[4][5] = {};
  float4 av[4];
  short8 bfr[10];

  a_load(xp, p, n0, 0, w, lane, av);
  a_store(&As[0][0], w, lane, av);
  b_load(Wp, w, lane, 0, bfr);
  __syncthreads();

  int buf = 0;
  #pragma unroll 1
  for(int kt=0;kt<74;++kt){
    a_load(xp, p, n0, kt+1, w, lane, av);
    do_mfma64(&As[buf][0], lane, bfr, acc);
    b_load(Wp, w, lane, kt+1, bfr);
    a_store(&As[buf^1][0], w, lane, av);
    __syncthreads();
    buf ^= 1;
  }
  do_mfma64(&As[buf][0], lane, bfr, acc);

  int j = lane & 15, rg = (lane>>4)*4;
  #pragma unroll
  for(int ni=0;ni<5;++ni){
    int col16 = w*5 + ni;
    int l, part, lr;
    if(col16<2){l=0;part=col16;lr=0;}
    else if(col16<6){int c=col16-2;l=1;part=c>>1;lr=c&1;}
    else if(col16<12){int c=col16-6;l=2;part=(c>=3);lr=part?(c-3):c;}
    else {int c=col16-12;l=3;part=c>>2;lr=c&3;}
    float bv = 0.f;
    if(!(part==1 && lr==0)) bv = bp.p[l*2+part][lr*80 + p*16 + j];
    long base = 655360L*(l+1)*(l+part);
    int nst = (l+1)*80;
    long ioff = base + lr*80 + p*16 + j;
    #pragma unroll
    for(int mi=0;mi<4;++mi){
      int n = n0 + mi*16 + rg;
      #pragma unroll
      for(int r=0;r<4;++r)
        out[ioff + (long)(n+r)*nst] = acc[mi][ni][r] + bv;
    }
  }
}

extern "C" void kernel_launch(void* const* d_in, const int* in_sizes, int n_in,
                              void* d_out, int out_size, void* d_ws, size_t ws_size,
                              hipStream_t stream){
  Ptrs8 xp, wp, bp;
  for(int i=0;i<8;i++){
    xp.p[i] = (const float*)d_in[i];
    wp.p[i] = (const float*)d_in[8+i];
    bp.p[i] = (const float*)d_in[16+i];
  }
  float* G = (float*)d_ws;
  ushort* W = (ushort*)((char*)d_ws + 65536);
  g_kernel<<<dim3(1), dim3(576), 0, stream>>>(G);
  w_kernel<<<dim3(30000), dim3(256), 0, stream>>>(G, wp, W);
  const size_t need = 16777216ull + 5ull*8192*9600;
  if(ws_size >= need){
    ushort* Xp = (ushort*)((char*)d_ws + 16777216);
    pack_kernel<<<dim3(8192), dim3(512), 0, stream>>>(xp, Xp);
    gemm_xp2<<<dim3(640), dim3(256), 0, stream>>>(Xp, W, bp, (float*)d_out);
  } else {
    gemm_direct<<<dim3(640), dim3(256), 0, stream>>>(xp, W, bp, (float*)d_out);
  }
}